// Round 1
// baseline (4111.855 us; speedup 1.0000x reference)
//
#include <hip/hip_runtime.h>
#include <hip/hip_bf16.h>
#include <math.h>
#include <stdint.h>

#define L      12
#define H      12
#define DMODEL 768
#define HDIM   64
#define DFF    3072
#define VOCAB  50257
#define VPAD   50304   // 393 * 128
#define SEQ    512
#define BATCH  4
#define MTOK   2048    // BATCH*SEQ

typedef __hip_bfloat16 bf16;
typedef __bf16 bf16x8 __attribute__((ext_vector_type(8)));
typedef float  f32x4  __attribute__((ext_vector_type(4)));

__device__ inline float bfbits2f(unsigned int u) {
    return __builtin_bit_cast(float, u << 16);
}
__device__ inline unsigned int f2bf_bits(float f) {
    __hip_bfloat16 h = __float2bfloat16(f);
    return (unsigned int)__builtin_bit_cast(unsigned short, h);
}
__device__ inline void unpack8(uint4 w, float* f) {
    f[0] = bfbits2f(w.x & 0xffffu); f[1] = bfbits2f(w.x >> 16);
    f[2] = bfbits2f(w.y & 0xffffu); f[3] = bfbits2f(w.y >> 16);
    f[4] = bfbits2f(w.z & 0xffffu); f[5] = bfbits2f(w.z >> 16);
    f[6] = bfbits2f(w.w & 0xffffu); f[7] = bfbits2f(w.w >> 16);
}

typedef __attribute__((address_space(1))) unsigned int as1_uint;
typedef __attribute__((address_space(3))) unsigned int as3_uint;

__device__ inline void load_lds_16B(const void* g, void* l) {
    __builtin_amdgcn_global_load_lds((as1_uint*)(uintptr_t)g,
                                     (as3_uint*)(uintptr_t)l, 16, 0, 0);
}

// ---------------- f32 -> bf16 conversion (with zero pad tail) ----------------
__global__ void cvt_pad_kernel(bf16* __restrict__ dst, const float* __restrict__ src,
                               long ns, long nt) {
    long i = (long)blockIdx.x * blockDim.x + threadIdx.x;
    long stride = (long)gridDim.x * blockDim.x;
    for (; i < nt; i += stride)
        dst[i] = (i < ns) ? __float2bfloat16(src[i]) : __float2bfloat16(0.f);
}

// ---------------- embedding: x = E[tok] + P ----------------
__global__ __launch_bounds__(256) void embed_kernel(float* __restrict__ x,
        const int* __restrict__ tok, const float* __restrict__ E,
        const float* __restrict__ P) {
    int i = blockIdx.x * 256 + threadIdx.x;      // grid is exact multiple
    int d  = i % DMODEL;
    int bs = i / DMODEL;
    int s  = bs % SEQ;
    x[i] = E[(size_t)tok[bs] * DMODEL + d] + P[s * DMODEL + d];
}

// ---------------- LayerNorm (f32 in, bf16 out) ----------------
__global__ __launch_bounds__(256) void ln_kernel(bf16* __restrict__ out,
        const float* __restrict__ x, const float* __restrict__ g,
        const float* __restrict__ b) {
    int row = blockIdx.x, tid = threadIdx.x;
    const float* xr = x + (size_t)row * DMODEL;
    float v0 = xr[tid], v1 = xr[tid + 256], v2 = xr[tid + 512];
    float s  = v0 + v1 + v2;
    float s2 = v0 * v0 + v1 * v1 + v2 * v2;
    #pragma unroll
    for (int o = 32; o > 0; o >>= 1) {
        s  += __shfl_down(s, o);
        s2 += __shfl_down(s2, o);
    }
    __shared__ float w1[4], w2[4];
    int wv = tid >> 6;
    if ((tid & 63) == 0) { w1[wv] = s; w2[wv] = s2; }
    __syncthreads();
    s  = w1[0] + w1[1] + w1[2] + w1[3];
    s2 = w2[0] + w2[1] + w2[2] + w2[3];
    float u    = s * (1.f / DMODEL);
    float var  = s2 * (1.f / DMODEL) - u * u;
    float rstd = rsqrtf(var + 1e-5f);
    size_t base = (size_t)row * DMODEL;
    out[base + tid]       = __float2bfloat16(g[tid]       * (v0 - u) * rstd + b[tid]);
    out[base + tid + 256] = __float2bfloat16(g[tid + 256] * (v1 - u) * rstd + b[tid + 256]);
    out[base + tid + 512] = __float2bfloat16(g[tid + 512] * (v2 - u) * rstd + b[tid + 512]);
}

// ---------------- GEMM: C[M,N] = A[M,K] * B[N,K]^T  (bf16 in, f32 acc) --------
// EPI 0: C bf16 (z-batched)      EPI 1: resid f32 += acc + bias
// EPI 2: C bf16 = gelu(acc+bias) EPI 3: C f32, col-bounded (LM head)
#define BM 128
#define BN 128
#define BKK 64

template<int EPI>
__global__ __launch_bounds__(256) void gemm_bt(
    const bf16* __restrict__ A, const bf16* __restrict__ Bmat, long strideBz,
    void* __restrict__ Cout, long strideCz,
    const float* __restrict__ bias, float* __restrict__ resid,
    int Mm, int Nn, int Kk, int Nstore)
{
    __shared__ __align__(16) bf16 As[BM * BKK];
    __shared__ __align__(16) bf16 Bs[BN * BKK];
    int tid = threadIdx.x;
    int lane = tid & 63, wave = tid >> 6;
    int bm = blockIdx.y * BM, bn = blockIdx.x * BN;
    int z = blockIdx.z;
    const bf16* Bz = Bmat + (size_t)z * strideBz;
    int wr = (wave >> 1) * 64, wc = (wave & 1) * 64;

    f32x4 acc[4][4];
    #pragma unroll
    for (int i = 0; i < 4; i++)
        #pragma unroll
        for (int j = 0; j < 4; j++) acc[i][j] = (f32x4){0.f, 0.f, 0.f, 0.f};

    for (int kt = 0; kt < Kk; kt += BKK) {
        #pragma unroll
        for (int i = 0; i < 4; i++) {
            int byte = i * 4096 + tid * 16;
            int r = byte >> 7;             // BKK*2 = 128 bytes per row
            int c = (byte & 127) >> 1;
            load_lds_16B(A  + (size_t)(bm + r) * Kk + kt + c, (char*)As + byte);
            load_lds_16B(Bz + (size_t)(bn + r) * Kk + kt + c, (char*)Bs + byte);
        }
        __syncthreads();
        #pragma unroll
        for (int kk = 0; kk < 2; ++kk) {
            bf16x8 af[4], bfr[4];
            int ro = lane & 15;
            int co = kk * 32 + (lane >> 4) * 8;
            #pragma unroll
            for (int mi = 0; mi < 4; mi++)
                af[mi] = *reinterpret_cast<const bf16x8*>(&As[(wr + mi * 16 + ro) * BKK + co]);
            #pragma unroll
            for (int ni = 0; ni < 4; ni++)
                bfr[ni] = *reinterpret_cast<const bf16x8*>(&Bs[(wc + ni * 16 + ro) * BKK + co]);
            #pragma unroll
            for (int mi = 0; mi < 4; mi++)
                #pragma unroll
                for (int ni = 0; ni < 4; ni++)
                    acc[mi][ni] = __builtin_amdgcn_mfma_f32_16x16x32_bf16(
                        af[mi], bfr[ni], acc[mi][ni], 0, 0, 0);
        }
        __syncthreads();
    }

    int rbase = bm + wr + ((lane >> 4) << 2);
    int cbase = bn + wc + (lane & 15);
    #pragma unroll
    for (int mi = 0; mi < 4; mi++) {
        #pragma unroll
        for (int ni = 0; ni < 4; ni++) {
            int col = cbase + ni * 16;
            #pragma unroll
            for (int r = 0; r < 4; r++) {
                int row = rbase + mi * 16 + r;
                float v = acc[mi][ni][r];
                if constexpr (EPI == 0) {
                    ((bf16*)Cout)[(size_t)z * strideCz + (size_t)row * Nn + col] =
                        __float2bfloat16(v);
                } else if constexpr (EPI == 1) {
                    size_t idx = (size_t)row * Nn + col;
                    resid[idx] = resid[idx] + v + bias[col];
                } else if constexpr (EPI == 2) {
                    float t = v + bias[col];
                    float gel = 0.5f * t * (1.f + erff(t * 0.70710678118654752f));
                    ((bf16*)Cout)[(size_t)row * Nn + col] = __float2bfloat16(gel);
                } else {
                    if (col < Nstore)
                        ((float*)Cout)[(size_t)row * Nstore + col] = v;
                }
            }
        }
    }
}

// ---------------- fused flash attention (vector ALU, f32) ----------------
// grid: B*H*(SEQ/32); block 256 = 4 waves; wave = 8 groups of 8 lanes,
// group handles one q row, lane j owns out dims [8j,8j+8).
#define NEGMASK -1e10f
#define SM_SCALE 0.125f

__global__ __launch_bounds__(256) void attn_kernel(
    bf16* __restrict__ o, const bf16* __restrict__ qb,
    const bf16* __restrict__ kb, const bf16* __restrict__ vb)
{
    __shared__ __align__(16) float Ks[64][64];
    __shared__ __align__(16) float Vs[64][64];
    int tid = threadIdx.x;
    int wave = tid >> 6, lane = tid & 63;
    int g = lane >> 3, j = lane & 7;
    int idx = blockIdx.x;
    int qt = idx & 15;
    int bh = idx >> 4;
    int h = bh % H, b = bh / H;
    int qrow = qt * 32 + wave * 8 + g;
    const size_t base = ((size_t)b * SEQ) * DMODEL + h * HDIM;

    float Qf[8];
    {
        uint4 w = *reinterpret_cast<const uint4*>(qb + base + (size_t)qrow * DMODEL + j * 8);
        unpack8(w, Qf);
    }
    float O[8] = {0.f, 0.f, 0.f, 0.f, 0.f, 0.f, 0.f, 0.f};
    float mx = -INFINITY, sm = 0.f;

    for (int mt = 0; mt < SEQ; mt += 64) {
        __syncthreads();
        #pragma unroll
        for (int pass = 0; pass < 2; ++pass) {
            int t = tid + pass * 256;
            int r = t >> 3, c0 = (t & 7) * 8;
            uint4 wk = *reinterpret_cast<const uint4*>(kb + base + (size_t)(mt + r) * DMODEL + c0);
            uint4 wv = *reinterpret_cast<const uint4*>(vb + base + (size_t)(mt + r) * DMODEL + c0);
            float kf[8], vf[8];
            unpack8(wk, kf);
            unpack8(wv, vf);
            #pragma unroll
            for (int e = 0; e < 8; e++) { Ks[r][c0 + e] = kf[e]; Vs[r][c0 + e] = vf[e]; }
        }
        __syncthreads();

        float p[8];
        #pragma unroll
        for (int mi = 0; mi < 64; ++mi) {
            const float* kr = &Ks[mi][j * 8];
            float d = Qf[0] * kr[0];
            #pragma unroll
            for (int e = 1; e < 8; ++e) d = fmaf(Qf[e], kr[e], d);
            d += __shfl_xor(d, 1);
            d += __shfl_xor(d, 2);
            d += __shfl_xor(d, 4);
            float sval = ((mt + mi) >= qrow) ? (d + NEGMASK) * SM_SCALE : d * SM_SCALE;
            if ((mi & 7) == j) p[mi >> 3] = sval;
        }
        float tmax = p[0];
        #pragma unroll
        for (int i = 1; i < 8; i++) tmax = fmaxf(tmax, p[i]);
        tmax = fmaxf(tmax, __shfl_xor(tmax, 1));
        tmax = fmaxf(tmax, __shfl_xor(tmax, 2));
        tmax = fmaxf(tmax, __shfl_xor(tmax, 4));
        float nm = fmaxf(mx, tmax);
        float f = __expf(mx - nm);
        float ps = 0.f;
        #pragma unroll
        for (int i = 0; i < 8; i++) { p[i] = __expf(p[i] - nm); ps += p[i]; }
        ps += __shfl_xor(ps, 1);
        ps += __shfl_xor(ps, 2);
        ps += __shfl_xor(ps, 4);
        sm = sm * f + ps;
        #pragma unroll
        for (int e = 0; e < 8; e++) O[e] *= f;
        #pragma unroll
        for (int mi = 0; mi < 64; ++mi) {
            float pm = __shfl(p[mi >> 3], (g << 3) | (mi & 7), 64);
            const float* vr = &Vs[mi][j * 8];
            #pragma unroll
            for (int e = 0; e < 8; e++) O[e] = fmaf(pm, vr[e], O[e]);
        }
        mx = nm;
    }

    float inv = 1.f / sm;
    uint4 wout;
    wout.x = f2bf_bits(O[0] * inv) | (f2bf_bits(O[1] * inv) << 16);
    wout.y = f2bf_bits(O[2] * inv) | (f2bf_bits(O[3] * inv) << 16);
    wout.z = f2bf_bits(O[4] * inv) | (f2bf_bits(O[5] * inv) << 16);
    wout.w = f2bf_bits(O[6] * inv) | (f2bf_bits(O[7] * inv) << 16);
    *reinterpret_cast<uint4*>(o + base + (size_t)qrow * DMODEL + j * 8) = wout;
}

// ---------------- host orchestration ----------------
extern "C" void kernel_launch(void* const* d_in, const int* in_sizes, int n_in,
                              void* d_out, int out_size, void* d_ws, size_t ws_size,
                              hipStream_t stream)
{
    (void)in_sizes; (void)n_in; (void)out_size; (void)ws_size;
    const int*   tokens = (const int*)d_in[0];
    const float* E    = (const float*)d_in[1];
    const float* P    = (const float*)d_in[2];
    const float* Wq   = (const float*)d_in[3];
    const float* Wk   = (const float*)d_in[4];
    const float* Wv   = (const float*)d_in[5];
    const float* Wo   = (const float*)d_in[6];
    const float* bo   = (const float*)d_in[7];
    const float* g1   = (const float*)d_in[8];
    const float* b1   = (const float*)d_in[9];
    const float* g2   = (const float*)d_in[10];
    const float* b2   = (const float*)d_in[11];
    const float* W1   = (const float*)d_in[12];
    const float* bff1 = (const float*)d_in[13];
    const float* W2   = (const float*)d_in[14];
    const float* bff2 = (const float*)d_in[15];
    const float* gf   = (const float*)d_in[16];
    const float* bfin = (const float*)d_in[17];

    char* ws = (char*)d_ws;
    size_t off = 0;
    auto alloc = [&](size_t bytes) -> void* {
        void* p = ws + off;
        off += (bytes + 255) & ~(size_t)255;
        return p;
    };
    float* x     = (float*)alloc((size_t)MTOK * DMODEL * 4);
    bf16* hbuf   = (bf16*)alloc((size_t)MTOK * DMODEL * 2);
    bf16* qkv    = (bf16*)alloc((size_t)3 * MTOK * DMODEL * 2);
    bf16* obuf   = (bf16*)alloc((size_t)MTOK * DMODEL * 2);
    bf16* ffb    = (bf16*)alloc((size_t)MTOK * DFF * 2);
    bf16* Eb     = (bf16*)alloc((size_t)VPAD * DMODEL * 2);
    bf16* Wqkv_b = (bf16*)alloc((size_t)3 * L * DMODEL * DMODEL * 2);
    bf16* Wo_b   = (bf16*)alloc((size_t)L * DMODEL * DMODEL * 2);
    bf16* W1_b   = (bf16*)alloc((size_t)L * DFF * DMODEL * 2);
    bf16* W2_b   = (bf16*)alloc((size_t)L * DMODEL * DFF * 2);

    long nE = (long)VOCAB * DMODEL;
    long nEp = (long)VPAD * DMODEL;
    cvt_pad_kernel<<<(unsigned)((nEp + 255) / 256), 256, 0, stream>>>(Eb, E, nE, nEp);
    long nW = (long)L * DMODEL * DMODEL;
    cvt_pad_kernel<<<(unsigned)((nW + 255) / 256), 256, 0, stream>>>(Wqkv_b,          Wq, nW, nW);
    cvt_pad_kernel<<<(unsigned)((nW + 255) / 256), 256, 0, stream>>>(Wqkv_b + nW,     Wk, nW, nW);
    cvt_pad_kernel<<<(unsigned)((nW + 255) / 256), 256, 0, stream>>>(Wqkv_b + 2 * nW, Wv, nW, nW);
    cvt_pad_kernel<<<(unsigned)((nW + 255) / 256), 256, 0, stream>>>(Wo_b,            Wo, nW, nW);
    long nF = (long)L * DFF * DMODEL;
    cvt_pad_kernel<<<(unsigned)((nF + 255) / 256), 256, 0, stream>>>(W1_b, W1, nF, nF);
    cvt_pad_kernel<<<(unsigned)((nF + 255) / 256), 256, 0, stream>>>(W2_b, W2, nF, nF);

    embed_kernel<<<MTOK * DMODEL / 256, 256, 0, stream>>>(x, tokens, E, P);

    for (int l = 0; l < L; ++l) {
        ln_kernel<<<MTOK, 256, 0, stream>>>(hbuf, x, g1 + l * DMODEL, b1 + l * DMODEL);
        gemm_bt<0><<<dim3(DMODEL / BN, MTOK / BM, 3), 256, 0, stream>>>(
            hbuf, Wqkv_b + (size_t)l * DMODEL * DMODEL, (long)L * DMODEL * DMODEL,
            qkv, (long)MTOK * DMODEL, nullptr, nullptr, MTOK, DMODEL, DMODEL, DMODEL);
        attn_kernel<<<BATCH * H * (SEQ / 32), 256, 0, stream>>>(
            obuf, qkv, qkv + (size_t)MTOK * DMODEL, qkv + (size_t)2 * MTOK * DMODEL);
        gemm_bt<1><<<dim3(DMODEL / BN, MTOK / BM, 1), 256, 0, stream>>>(
            obuf, Wo_b + (size_t)l * DMODEL * DMODEL, 0,
            nullptr, 0, bo + l * DMODEL, x, MTOK, DMODEL, DMODEL, DMODEL);
        ln_kernel<<<MTOK, 256, 0, stream>>>(hbuf, x, g2 + l * DMODEL, b2 + l * DMODEL);
        gemm_bt<2><<<dim3(DFF / BN, MTOK / BM, 1), 256, 0, stream>>>(
            hbuf, W1_b + (size_t)l * DFF * DMODEL, 0,
            ffb, 0, bff1 + l * DFF, nullptr, MTOK, DFF, DMODEL, DFF);
        gemm_bt<1><<<dim3(DMODEL / BN, MTOK / BM, 1), 256, 0, stream>>>(
            ffb, W2_b + (size_t)l * DMODEL * DFF, 0,
            nullptr, 0, bff2 + l * DMODEL, x, MTOK, DMODEL, DFF, DMODEL);
    }
    ln_kernel<<<MTOK, 256, 0, stream>>>(hbuf, x, gf, bfin);
    gemm_bt<3><<<dim3(VPAD / BN, MTOK / BM, 1), 256, 0, stream>>>(
        hbuf, Eb, 0, d_out, 0, nullptr, nullptr, MTOK, VPAD, DMODEL, VOCAB);
}

// Round 2
// 3117.584 us; speedup vs baseline: 1.3189x; 1.3189x over previous
//
#include <hip/hip_runtime.h>
#include <hip/hip_bf16.h>
#include <math.h>
#include <stdint.h>

#define L      12
#define H      12
#define DMODEL 768
#define HDIM   64
#define DFF    3072
#define VOCAB  50257
#define VPAD   50304   // 393 * 128
#define SEQ    512
#define BATCH  4
#define MTOK   2048    // BATCH*SEQ

typedef __hip_bfloat16 bf16;
typedef __bf16 bf16x8 __attribute__((ext_vector_type(8)));
typedef float  f32x4  __attribute__((ext_vector_type(4)));

__device__ inline float bfbits2f(unsigned int u) {
    return __builtin_bit_cast(float, u << 16);
}
__device__ inline unsigned int f2bf_bits(float f) {
    __hip_bfloat16 h = __float2bfloat16(f);
    return (unsigned int)__builtin_bit_cast(unsigned short, h);
}
__device__ inline void unpack8(uint4 w, float* f) {
    f[0] = bfbits2f(w.x & 0xffffu); f[1] = bfbits2f(w.x >> 16);
    f[2] = bfbits2f(w.y & 0xffffu); f[3] = bfbits2f(w.y >> 16);
    f[4] = bfbits2f(w.z & 0xffffu); f[5] = bfbits2f(w.z >> 16);
    f[6] = bfbits2f(w.w & 0xffffu); f[7] = bfbits2f(w.w >> 16);
}

typedef __attribute__((address_space(1))) unsigned int as1_uint;
typedef __attribute__((address_space(3))) unsigned int as3_uint;

__device__ inline void load_lds_16B(const void* g, void* l) {
    __builtin_amdgcn_global_load_lds((as1_uint*)(uintptr_t)g,
                                     (as3_uint*)(uintptr_t)l, 16, 0, 0);
}

// XCD-chunked bijective swizzle (nwg % 8 == 0 for every grid we launch)
__device__ inline int xcd_swz(int raw, int nwg) {
    return (raw & 7) * (nwg >> 3) + (raw >> 3);
}

// ---------------- f32 -> bf16 conversion, vectorized, with zero pad tail ------
// ns and nt are multiples of 8.
__global__ void cvt_pad_kernel(bf16* __restrict__ dst, const float* __restrict__ src,
                               long ns, long nt) {
    long i8 = ((long)blockIdx.x * blockDim.x + threadIdx.x) * 8;
    long stride = (long)gridDim.x * blockDim.x * 8;
    for (; i8 < nt; i8 += stride) {
        uint4 out;
        if (i8 < ns) {
            float4 a = *reinterpret_cast<const float4*>(src + i8);
            float4 b = *reinterpret_cast<const float4*>(src + i8 + 4);
            out.x = f2bf_bits(a.x) | (f2bf_bits(a.y) << 16);
            out.y = f2bf_bits(a.z) | (f2bf_bits(a.w) << 16);
            out.z = f2bf_bits(b.x) | (f2bf_bits(b.y) << 16);
            out.w = f2bf_bits(b.z) | (f2bf_bits(b.w) << 16);
        } else {
            out = (uint4){0u, 0u, 0u, 0u};
        }
        *reinterpret_cast<uint4*>(dst + i8) = out;
    }
}

// ---------------- embedding: x = E[tok] + P ----------------
__global__ __launch_bounds__(256) void embed_kernel(float* __restrict__ x,
        const int* __restrict__ tok, const float* __restrict__ E,
        const float* __restrict__ P) {
    int i = blockIdx.x * 256 + threadIdx.x;      // grid is exact multiple
    int d  = i % DMODEL;
    int bs = i / DMODEL;
    int s  = bs % SEQ;
    x[i] = E[(size_t)tok[bs] * DMODEL + d] + P[s * DMODEL + d];
}

// ---------------- LayerNorm (f32 in, bf16 out) ----------------
__global__ __launch_bounds__(256) void ln_kernel(bf16* __restrict__ out,
        const float* __restrict__ x, const float* __restrict__ g,
        const float* __restrict__ b) {
    int row = blockIdx.x, tid = threadIdx.x;
    const float* xr = x + (size_t)row * DMODEL;
    float v0 = xr[tid], v1 = xr[tid + 256], v2 = xr[tid + 512];
    float s  = v0 + v1 + v2;
    float s2 = v0 * v0 + v1 * v1 + v2 * v2;
    #pragma unroll
    for (int o = 32; o > 0; o >>= 1) {
        s  += __shfl_down(s, o);
        s2 += __shfl_down(s2, o);
    }
    __shared__ float w1[4], w2[4];
    int wv = tid >> 6;
    if ((tid & 63) == 0) { w1[wv] = s; w2[wv] = s2; }
    __syncthreads();
    s  = w1[0] + w1[1] + w1[2] + w1[3];
    s2 = w2[0] + w2[1] + w2[2] + w2[3];
    float u    = s * (1.f / DMODEL);
    float var  = s2 * (1.f / DMODEL) - u * u;
    float rstd = rsqrtf(var + 1e-5f);
    size_t base = (size_t)row * DMODEL;
    out[base + tid]       = __float2bfloat16(g[tid]       * (v0 - u) * rstd + b[tid]);
    out[base + tid + 256] = __float2bfloat16(g[tid + 256] * (v1 - u) * rstd + b[tid + 256]);
    out[base + tid + 512] = __float2bfloat16(g[tid + 512] * (v2 - u) * rstd + b[tid + 512]);
}

// ------- fused split-K reduce + bias + residual add + LayerNorm -> bf16 -------
// x[row] += bias + sum_s part[s][row]; then hout = LN(x[row]; g,b)
__global__ __launch_bounds__(256) void reduce_ln_kernel(
        float* __restrict__ x, const float* __restrict__ part, int S,
        const float* __restrict__ bias, const float* __restrict__ g,
        const float* __restrict__ b, bf16* __restrict__ hout) {
    int row = blockIdx.x, tid = threadIdx.x;
    float v[3];
    #pragma unroll
    for (int e = 0; e < 3; e++) {
        int c = tid + e * 256;
        size_t idx = (size_t)row * DMODEL + c;
        float acc = x[idx] + bias[c];
        for (int s = 0; s < S; s++)
            acc += part[((size_t)s * MTOK + row) * DMODEL + c];
        v[e] = acc;
        x[idx] = acc;
    }
    float s1 = v[0] + v[1] + v[2];
    float s2 = v[0] * v[0] + v[1] * v[1] + v[2] * v[2];
    #pragma unroll
    for (int o = 32; o > 0; o >>= 1) {
        s1 += __shfl_down(s1, o);
        s2 += __shfl_down(s2, o);
    }
    __shared__ float w1[4], w2[4];
    int wv = tid >> 6;
    if ((tid & 63) == 0) { w1[wv] = s1; w2[wv] = s2; }
    __syncthreads();
    s1 = w1[0] + w1[1] + w1[2] + w1[3];
    s2 = w2[0] + w2[1] + w2[2] + w2[3];
    float u    = s1 * (1.f / DMODEL);
    float var  = s2 * (1.f / DMODEL) - u * u;
    float rstd = rsqrtf(var + 1e-5f);
    size_t base = (size_t)row * DMODEL;
    #pragma unroll
    for (int e = 0; e < 3; e++) {
        int c = tid + e * 256;
        hout[base + c] = __float2bfloat16(g[c] * (v[e] - u) * rstd + b[c]);
    }
}

// ---------------- GEMM: C[M,N] = A[M,K] * B[N,K]^T  (bf16 in, f32 acc) --------
// BM=128 fixed; BN_ is 64 (layer gemms) or 128 (LM head).
// EPI 0: C bf16, z-batched B+C (QKV)
// EPI 2: C bf16 = gelu(acc+bias)            (FF1)
// EPI 3: C f32, col-bounded to Nstore       (LM head)
// EPI 4: C f32 partial [z][M][N], z = K-slice (split-K; proj / FF2)
#define BM 128
#define BKK 64

template<int BN_, int EPI>
__global__ __launch_bounds__(256) void gemm_bt(
    const bf16* __restrict__ A, const bf16* __restrict__ Bmat, long strideBz,
    void* __restrict__ Cout, long strideCz,
    const float* __restrict__ bias,
    int Mm, int Nn, int Kk, int Nstore, int kslice)
{
    constexpr int NF = BN_ / 32;           // B frags per wave (wave tile 64 x BN_/2)
    __shared__ __align__(16) bf16 As[BM * BKK];
    __shared__ __align__(16) bf16 Bs[BN_ * BKK];
    int tid = threadIdx.x;
    int lane = tid & 63, wave = tid >> 6;

    int Mtiles = Mm / BM;
    int id = xcd_swz(blockIdx.x, gridDim.x);        // M-fastest within XCD chunk
    int bm = (id % Mtiles) * BM;
    int bn = (id / Mtiles) * BN_;
    int z = blockIdx.z;
    const bf16* Bz = Bmat + (size_t)z * strideBz;
    int wr = (wave >> 1) * 64, wc = (wave & 1) * (BN_ / 2);

    int k0 = (EPI == 4) ? z * kslice : 0;
    int k1 = (EPI == 4) ? k0 + kslice : Kk;

    f32x4 acc[4][NF];
    #pragma unroll
    for (int i = 0; i < 4; i++)
        #pragma unroll
        for (int j = 0; j < NF; j++) acc[i][j] = (f32x4){0.f, 0.f, 0.f, 0.f};

    const int swz_rd = (lane & 7) << 4;    // row-dependent XOR for ds_read

    for (int kt = k0; kt < k1; kt += BKK) {
        // stage A (128 rows) + B (BN_ rows), rows are 128 B; source pre-swizzled
        #pragma unroll
        for (int i = 0; i < 4; i++) {
            int byte = i * 4096 + tid * 16;
            int r = byte >> 7;
            int cb = byte & 127;
            int scb = cb ^ ((r & 7) << 4);
            load_lds_16B(A + (size_t)(bm + r) * Kk + kt + (scb >> 1), (char*)As + byte);
        }
        #pragma unroll
        for (int i = 0; i < BN_ / 32; i++) {
            int byte = i * 4096 + tid * 16;
            int r = byte >> 7;
            int cb = byte & 127;
            int scb = cb ^ ((r & 7) << 4);
            load_lds_16B(Bz + (size_t)(bn + r) * Kk + kt + (scb >> 1), (char*)Bs + byte);
        }
        __syncthreads();
        #pragma unroll
        for (int kk = 0; kk < 2; ++kk) {
            bf16x8 af[4], bfr[NF];
            int ro = lane & 15;
            int cob = kk * 64 + (lane >> 4) * 16;   // byte offset in row
            #pragma unroll
            for (int mi = 0; mi < 4; mi++) {
                int row = wr + mi * 16 + ro;
                af[mi] = *reinterpret_cast<const bf16x8*>(
                    (const char*)As + row * 128 + (cob ^ swz_rd));
            }
            #pragma unroll
            for (int ni = 0; ni < NF; ni++) {
                int row = wc + ni * 16 + ro;
                bfr[ni] = *reinterpret_cast<const bf16x8*>(
                    (const char*)Bs + row * 128 + (cob ^ swz_rd));
            }
            #pragma unroll
            for (int mi = 0; mi < 4; mi++)
                #pragma unroll
                for (int ni = 0; ni < NF; ni++)
                    acc[mi][ni] = __builtin_amdgcn_mfma_f32_16x16x32_bf16(
                        af[mi], bfr[ni], acc[mi][ni], 0, 0, 0);
        }
        __syncthreads();
    }

    int rbase = bm + wr + ((lane >> 4) << 2);
    int cbase = bn + wc + (lane & 15);
    #pragma unroll
    for (int mi = 0; mi < 4; mi++) {
        #pragma unroll
        for (int ni = 0; ni < NF; ni++) {
            int col = cbase + ni * 16;
            #pragma unroll
            for (int r = 0; r < 4; r++) {
                int row = rbase + mi * 16 + r;
                float v = acc[mi][ni][r];
                if constexpr (EPI == 0) {
                    ((bf16*)Cout)[(size_t)z * strideCz + (size_t)row * Nn + col] =
                        __float2bfloat16(v);
                } else if constexpr (EPI == 2) {
                    float t = v + bias[col];
                    float gel = 0.5f * t * (1.f + erff(t * 0.70710678118654752f));
                    ((bf16*)Cout)[(size_t)row * Nn + col] = __float2bfloat16(gel);
                } else if constexpr (EPI == 3) {
                    if (col < Nstore)
                        ((float*)Cout)[(size_t)row * Nstore + col] = v;
                } else { // EPI == 4
                    ((float*)Cout)[(size_t)z * strideCz + (size_t)row * Nn + col] = v;
                }
            }
        }
    }
}

// ---------------- fused flash attention (vector ALU, f32) ----------------
#define NEGMASK -1e10f
#define SM_SCALE 0.125f

__global__ __launch_bounds__(256) void attn_kernel(
    bf16* __restrict__ o, const bf16* __restrict__ qb,
    const bf16* __restrict__ kb, const bf16* __restrict__ vb)
{
    __shared__ __align__(16) float Ks[64][64];
    __shared__ __align__(16) float Vs[64][64];
    int tid = threadIdx.x;
    int wave = tid >> 6, lane = tid & 63;
    int g = lane >> 3, j = lane & 7;
    int idx = xcd_swz(blockIdx.x, gridDim.x);   // keep each (b,h)'s K/V on one XCD
    int qt = idx & 15;
    int bh = idx >> 4;
    int h = bh % H, b = bh / H;
    int qrow = qt * 32 + wave * 8 + g;
    const size_t base = ((size_t)b * SEQ) * DMODEL + h * HDIM;

    float Qf[8];
    {
        uint4 w = *reinterpret_cast<const uint4*>(qb + base + (size_t)qrow * DMODEL + j * 8);
        unpack8(w, Qf);
    }
    float O[8] = {0.f, 0.f, 0.f, 0.f, 0.f, 0.f, 0.f, 0.f};
    float mx = -INFINITY, sm = 0.f;

    for (int mt = 0; mt < SEQ; mt += 64) {
        __syncthreads();
        #pragma unroll
        for (int pass = 0; pass < 2; ++pass) {
            int t = tid + pass * 256;
            int r = t >> 3, c0 = (t & 7) * 8;
            uint4 wk = *reinterpret_cast<const uint4*>(kb + base + (size_t)(mt + r) * DMODEL + c0);
            uint4 wv = *reinterpret_cast<const uint4*>(vb + base + (size_t)(mt + r) * DMODEL + c0);
            float kf[8], vf[8];
            unpack8(wk, kf);
            unpack8(wv, vf);
            #pragma unroll
            for (int e = 0; e < 8; e++) { Ks[r][c0 + e] = kf[e]; Vs[r][c0 + e] = vf[e]; }
        }
        __syncthreads();

        float p[8];
        #pragma unroll
        for (int mi = 0; mi < 64; ++mi) {
            const float* kr = &Ks[mi][j * 8];
            float d = Qf[0] * kr[0];
            #pragma unroll
            for (int e = 1; e < 8; ++e) d = fmaf(Qf[e], kr[e], d);
            d += __shfl_xor(d, 1);
            d += __shfl_xor(d, 2);
            d += __shfl_xor(d, 4);
            float sval = ((mt + mi) >= qrow) ? (d + NEGMASK) * SM_SCALE : d * SM_SCALE;
            if ((mi & 7) == j) p[mi >> 3] = sval;
        }
        float tmax = p[0];
        #pragma unroll
        for (int i = 1; i < 8; i++) tmax = fmaxf(tmax, p[i]);
        tmax = fmaxf(tmax, __shfl_xor(tmax, 1));
        tmax = fmaxf(tmax, __shfl_xor(tmax, 2));
        tmax = fmaxf(tmax, __shfl_xor(tmax, 4));
        float nm = fmaxf(mx, tmax);
        float f = __expf(mx - nm);
        float ps = 0.f;
        #pragma unroll
        for (int i = 0; i < 8; i++) { p[i] = __expf(p[i] - nm); ps += p[i]; }
        ps += __shfl_xor(ps, 1);
        ps += __shfl_xor(ps, 2);
        ps += __shfl_xor(ps, 4);
        sm = sm * f + ps;
        #pragma unroll
        for (int e = 0; e < 8; e++) O[e] *= f;
        #pragma unroll
        for (int mi = 0; mi < 64; ++mi) {
            float pm = __shfl(p[mi >> 3], (g << 3) | (mi & 7), 64);
            const float* vr = &Vs[mi][j * 8];
            #pragma unroll
            for (int e = 0; e < 8; e++) O[e] = fmaf(pm, vr[e], O[e]);
        }
        mx = nm;
    }

    float inv = 1.f / sm;
    uint4 wout;
    wout.x = f2bf_bits(O[0] * inv) | (f2bf_bits(O[1] * inv) << 16);
    wout.y = f2bf_bits(O[2] * inv) | (f2bf_bits(O[3] * inv) << 16);
    wout.z = f2bf_bits(O[4] * inv) | (f2bf_bits(O[5] * inv) << 16);
    wout.w = f2bf_bits(O[6] * inv) | (f2bf_bits(O[7] * inv) << 16);
    *reinterpret_cast<uint4*>(o + base + (size_t)qrow * DMODEL + j * 8) = wout;
}

// ---------------- host orchestration ----------------
extern "C" void kernel_launch(void* const* d_in, const int* in_sizes, int n_in,
                              void* d_out, int out_size, void* d_ws, size_t ws_size,
                              hipStream_t stream)
{
    (void)in_sizes; (void)n_in; (void)out_size; (void)ws_size;
    const int*   tokens = (const int*)d_in[0];
    const float* E    = (const float*)d_in[1];
    const float* P    = (const float*)d_in[2];
    const float* Wq   = (const float*)d_in[3];
    const float* Wk   = (const float*)d_in[4];
    const float* Wv   = (const float*)d_in[5];
    const float* Wo   = (const float*)d_in[6];
    const float* bo   = (const float*)d_in[7];
    const float* g1   = (const float*)d_in[8];
    const float* b1   = (const float*)d_in[9];
    const float* g2   = (const float*)d_in[10];
    const float* b2   = (const float*)d_in[11];
    const float* W1   = (const float*)d_in[12];
    const float* bff1 = (const float*)d_in[13];
    const float* W2   = (const float*)d_in[14];
    const float* bff2 = (const float*)d_in[15];
    const float* gf   = (const float*)d_in[16];
    const float* bfin = (const float*)d_in[17];

    char* ws = (char*)d_ws;
    size_t off = 0;
    auto alloc = [&](size_t bytes) -> void* {
        void* p = ws + off;
        off += (bytes + 255) & ~(size_t)255;
        return p;
    };
    float* x     = (float*)alloc((size_t)MTOK * DMODEL * 4);
    bf16* hbuf   = (bf16*)alloc((size_t)MTOK * DMODEL * 2);
    bf16* qkv    = (bf16*)alloc((size_t)3 * MTOK * DMODEL * 2);
    bf16* obuf   = (bf16*)alloc((size_t)MTOK * DMODEL * 2);
    bf16* ffb    = (bf16*)alloc((size_t)MTOK * DFF * 2);
    float* part  = (float*)alloc((size_t)6 * MTOK * DMODEL * 4);
    bf16* Eb     = (bf16*)alloc((size_t)VPAD * DMODEL * 2);
    bf16* Wqkv_b = (bf16*)alloc((size_t)3 * L * DMODEL * DMODEL * 2);
    bf16* Wo_b   = (bf16*)alloc((size_t)L * DMODEL * DMODEL * 2);
    bf16* W1_b   = (bf16*)alloc((size_t)L * DFF * DMODEL * 2);
    bf16* W2_b   = (bf16*)alloc((size_t)L * DMODEL * DFF * 2);

    long nE  = (long)VOCAB * DMODEL;
    long nEp = (long)VPAD * DMODEL;
    cvt_pad_kernel<<<2048, 256, 0, stream>>>(Eb, E, nE, nEp);
    long nW = (long)L * DMODEL * DMODEL;
    cvt_pad_kernel<<<2048, 256, 0, stream>>>(Wqkv_b,          Wq, nW, nW);
    cvt_pad_kernel<<<2048, 256, 0, stream>>>(Wqkv_b + nW,     Wk, nW, nW);
    cvt_pad_kernel<<<2048, 256, 0, stream>>>(Wqkv_b + 2 * nW, Wv, nW, nW);
    cvt_pad_kernel<<<2048, 256, 0, stream>>>(Wo_b,            Wo, nW, nW);
    long nF = (long)L * DFF * DMODEL;
    cvt_pad_kernel<<<2048, 256, 0, stream>>>(W1_b, W1, nF, nF);
    cvt_pad_kernel<<<2048, 256, 0, stream>>>(W2_b, W2, nF, nF);

    embed_kernel<<<MTOK * DMODEL / 256, 256, 0, stream>>>(x, tokens, E, P);
    ln_kernel<<<MTOK, 256, 0, stream>>>(hbuf, x, g1, b1);

    const long pstride = (long)MTOK * DMODEL;
    for (int l = 0; l < L; ++l) {
        // QKV: M=2048, N=768, K=768, z-batched over {Q,K,V}; grid 192*3
        gemm_bt<64, 0><<<dim3(16 * 12, 1, 3), 256, 0, stream>>>(
            hbuf, Wqkv_b + (size_t)l * DMODEL * DMODEL, (long)L * DMODEL * DMODEL,
            qkv, pstride, nullptr, MTOK, DMODEL, DMODEL, 0, 0);
        attn_kernel<<<BATCH * H * (SEQ / 32), 256, 0, stream>>>(
            obuf, qkv, qkv + pstride, qkv + 2 * pstride);
        // proj: split-K 3 -> partials
        gemm_bt<64, 4><<<dim3(16 * 12, 1, 3), 256, 0, stream>>>(
            obuf, Wo_b + (size_t)l * DMODEL * DMODEL, 0,
            part, pstride, nullptr, MTOK, DMODEL, DMODEL, 0, DMODEL / 3);
        reduce_ln_kernel<<<MTOK, 256, 0, stream>>>(
            x, part, 3, bo + l * DMODEL, g2 + l * DMODEL, b2 + l * DMODEL, hbuf);
        // FF1: M=2048, N=3072, K=768, gelu; grid 768
        gemm_bt<64, 2><<<dim3(16 * 48, 1, 1), 256, 0, stream>>>(
            hbuf, W1_b + (size_t)l * DFF * DMODEL, 0,
            ffb, 0, bff1 + l * DFF, MTOK, DFF, DMODEL, 0, 0);
        // FF2: split-K 6 -> partials
        gemm_bt<64, 4><<<dim3(16 * 12, 1, 6), 256, 0, stream>>>(
            ffb, W2_b + (size_t)l * DMODEL * DFF, 0,
            part, pstride, nullptr, MTOK, DMODEL, DFF, 0, DFF / 6);
        const float* ng = (l < L - 1) ? (g1 + (l + 1) * DMODEL) : gf;
        const float* nb = (l < L - 1) ? (b1 + (l + 1) * DMODEL) : bfin;
        reduce_ln_kernel<<<MTOK, 256, 0, stream>>>(
            x, part, 6, bff2 + l * DMODEL, ng, nb, hbuf);
    }
    // LM head: M=2048, N=50304 (bounded store to 50257), K=768
    gemm_bt<128, 3><<<dim3(16 * 393, 1, 1), 256, 0, stream>>>(
        hbuf, Eb, 0, d_out, 0, nullptr, MTOK, VPAD, DMODEL, VOCAB, 0);
}

// Round 3
// 2950.303 us; speedup vs baseline: 1.3937x; 1.0567x over previous
//
#include <hip/hip_runtime.h>
#include <hip/hip_bf16.h>
#include <math.h>
#include <stdint.h>

#define L      12
#define H      12
#define DMODEL 768
#define HDIM   64
#define DFF    3072
#define VOCAB  50257
#define VPAD   50304   // 393 * 128
#define SEQ    512
#define BATCH  4
#define MTOK   2048    // BATCH*SEQ

typedef __hip_bfloat16 bf16;
typedef __bf16 bf16x8 __attribute__((ext_vector_type(8)));
typedef float  f32x4  __attribute__((ext_vector_type(4)));

__device__ inline float bfbits2f(unsigned int u) {
    return __builtin_bit_cast(float, u << 16);
}
__device__ inline unsigned int f2bf_bits(float f) {
    __hip_bfloat16 h = __float2bfloat16(f);
    return (unsigned int)__builtin_bit_cast(unsigned short, h);
}
__device__ inline void unpack8(uint4 w, float* f) {
    f[0] = bfbits2f(w.x & 0xffffu); f[1] = bfbits2f(w.x >> 16);
    f[2] = bfbits2f(w.y & 0xffffu); f[3] = bfbits2f(w.y >> 16);
    f[4] = bfbits2f(w.z & 0xffffu); f[5] = bfbits2f(w.z >> 16);
    f[6] = bfbits2f(w.w & 0xffffu); f[7] = bfbits2f(w.w >> 16);
}

typedef __attribute__((address_space(1))) unsigned int as1_uint;
typedef __attribute__((address_space(3))) unsigned int as3_uint;

__device__ inline void load_lds_16B(const void* g, void* l) {
    __builtin_amdgcn_global_load_lds((as1_uint*)(uintptr_t)g,
                                     (as3_uint*)(uintptr_t)l, 16, 0, 0);
}

// XCD-chunked bijective swizzle (nwg % 8 == 0 for every grid we launch)
__device__ inline int xcd_swz(int raw, int nwg) {
    return (raw & 7) * (nwg >> 3) + (raw >> 3);
}

// ---------------- f32 -> bf16 conversion, vectorized, with zero pad tail ------
__global__ void cvt_pad_kernel(bf16* __restrict__ dst, const float* __restrict__ src,
                               long ns, long nt) {
    long i8 = ((long)blockIdx.x * blockDim.x + threadIdx.x) * 8;
    long stride = (long)gridDim.x * blockDim.x * 8;
    for (; i8 < nt; i8 += stride) {
        uint4 out;
        if (i8 < ns) {
            float4 a = *reinterpret_cast<const float4*>(src + i8);
            float4 b = *reinterpret_cast<const float4*>(src + i8 + 4);
            out.x = f2bf_bits(a.x) | (f2bf_bits(a.y) << 16);
            out.y = f2bf_bits(a.z) | (f2bf_bits(a.w) << 16);
            out.z = f2bf_bits(b.x) | (f2bf_bits(b.y) << 16);
            out.w = f2bf_bits(b.z) | (f2bf_bits(b.w) << 16);
        } else {
            out = (uint4){0u, 0u, 0u, 0u};
        }
        *reinterpret_cast<uint4*>(dst + i8) = out;
    }
}

// ---------------- fused embedding + LayerNorm ----------------
// x[row] = E[tok[row]] + P[row%SEQ];  hout[row] = LN(x[row]; g,b)
__global__ __launch_bounds__(256) void embed_ln_kernel(
        float* __restrict__ x, bf16* __restrict__ hout,
        const int* __restrict__ tok, const float* __restrict__ E,
        const float* __restrict__ P, const float* __restrict__ g,
        const float* __restrict__ b) {
    int row = blockIdx.x, tid = threadIdx.x;
    int s = row % SEQ;
    size_t ebase = (size_t)tok[row] * DMODEL;
    float v[3];
    #pragma unroll
    for (int e = 0; e < 3; e++) {
        int c = tid + e * 256;
        v[e] = E[ebase + c] + P[s * DMODEL + c];
        x[(size_t)row * DMODEL + c] = v[e];
    }
    float s1 = v[0] + v[1] + v[2];
    float s2 = v[0] * v[0] + v[1] * v[1] + v[2] * v[2];
    #pragma unroll
    for (int o = 32; o > 0; o >>= 1) {
        s1 += __shfl_down(s1, o);
        s2 += __shfl_down(s2, o);
    }
    __shared__ float w1[4], w2[4];
    int wv = tid >> 6;
    if ((tid & 63) == 0) { w1[wv] = s1; w2[wv] = s2; }
    __syncthreads();
    s1 = w1[0] + w1[1] + w1[2] + w1[3];
    s2 = w2[0] + w2[1] + w2[2] + w2[3];
    float u    = s1 * (1.f / DMODEL);
    float var  = s2 * (1.f / DMODEL) - u * u;
    float rstd = rsqrtf(var + 1e-5f);
    size_t base = (size_t)row * DMODEL;
    #pragma unroll
    for (int e = 0; e < 3; e++) {
        int c = tid + e * 256;
        hout[base + c] = __float2bfloat16(g[c] * (v[e] - u) * rstd + b[c]);
    }
}

// ------- fused split-K reduce + bias + residual add + LayerNorm -> bf16 -------
__global__ __launch_bounds__(256) void reduce_ln_kernel(
        float* __restrict__ x, const float* __restrict__ part, int S,
        const float* __restrict__ bias, const float* __restrict__ g,
        const float* __restrict__ b, bf16* __restrict__ hout) {
    int row = blockIdx.x, tid = threadIdx.x;
    float v[3];
    #pragma unroll
    for (int e = 0; e < 3; e++) {
        int c = tid + e * 256;
        size_t idx = (size_t)row * DMODEL + c;
        float acc = x[idx] + bias[c];
        for (int s = 0; s < S; s++)
            acc += part[((size_t)s * MTOK + row) * DMODEL + c];
        v[e] = acc;
        x[idx] = acc;
    }
    float s1 = v[0] + v[1] + v[2];
    float s2 = v[0] * v[0] + v[1] * v[1] + v[2] * v[2];
    #pragma unroll
    for (int o = 32; o > 0; o >>= 1) {
        s1 += __shfl_down(s1, o);
        s2 += __shfl_down(s2, o);
    }
    __shared__ float w1[4], w2[4];
    int wv = tid >> 6;
    if ((tid & 63) == 0) { w1[wv] = s1; w2[wv] = s2; }
    __syncthreads();
    s1 = w1[0] + w1[1] + w1[2] + w1[3];
    s2 = w2[0] + w2[1] + w2[2] + w2[3];
    float u    = s1 * (1.f / DMODEL);
    float var  = s2 * (1.f / DMODEL) - u * u;
    float rstd = rsqrtf(var + 1e-5f);
    size_t base = (size_t)row * DMODEL;
    #pragma unroll
    for (int e = 0; e < 3; e++) {
        int c = tid + e * 256;
        hout[base + c] = __float2bfloat16(g[c] * (v[e] - u) * rstd + b[c]);
    }
}

// ---------------- GEMM: C[M,N] = A[M,K] * B[N,K]^T  (bf16 in, f32 acc) --------
// Double-buffered prefetch (T3-minimum): stage(next) -> compute(cur) -> 1 barrier.
// EPI 0: C bf16, z-batched B+C (QKV)
// EPI 2: C bf16 = gelu(acc+bias)            (FF1)
// EPI 3: C f32, col-bounded to Nstore       (LM head)
// EPI 4: C f32 partial [z][M][N], z = K-slice (split-K; proj / FF2)
#define BM 128
#define BKK 64

template<int BN_, int EPI>
__global__ __launch_bounds__(256) void gemm_bt(
    const bf16* __restrict__ A, const bf16* __restrict__ Bmat, long strideBz,
    void* __restrict__ Cout, long strideCz,
    const float* __restrict__ bias,
    int Mm, int Nn, int Kk, int Nstore, int kslice)
{
    constexpr int NF = BN_ / 32;           // B frags per wave (wave tile 64 x BN_/2)
    __shared__ __align__(16) bf16 As[2][BM * BKK];
    __shared__ __align__(16) bf16 Bs[2][BN_ * BKK];
    int tid = threadIdx.x;
    int lane = tid & 63, wave = tid >> 6;

    int Mtiles = Mm / BM;
    int id = xcd_swz(blockIdx.x, gridDim.x);        // M-fastest within XCD chunk
    int bm = (id % Mtiles) * BM;
    int bn = (id / Mtiles) * BN_;
    int z = blockIdx.z;
    const bf16* Bz = Bmat + (size_t)z * strideBz;
    int wr = (wave >> 1) * 64, wc = (wave & 1) * (BN_ / 2);

    int k0 = (EPI == 4) ? z * kslice : 0;
    int nt = ((EPI == 4) ? kslice : Kk) / BKK;

    f32x4 acc[4][NF];
    #pragma unroll
    for (int i = 0; i < 4; i++)
        #pragma unroll
        for (int j = 0; j < NF; j++) acc[i][j] = (f32x4){0.f, 0.f, 0.f, 0.f};

    // stage: global -> LDS, source pre-swizzled so linear LDS dest + swizzled
    // ds_read form the same involution (rule #21)
    auto stage = [&](int buf, int kt) {
        #pragma unroll
        for (int i = 0; i < 4; i++) {
            int byte = i * 4096 + tid * 16;
            int r = byte >> 7;                       // 128 B per row
            int scb = (byte & 127) ^ ((r & 7) << 4);
            load_lds_16B(A + (size_t)(bm + r) * Kk + kt + (scb >> 1),
                         (char*)As[buf] + byte);
        }
        #pragma unroll
        for (int i = 0; i < BN_ / 32; i++) {
            int byte = i * 4096 + tid * 16;
            int r = byte >> 7;
            int scb = (byte & 127) ^ ((r & 7) << 4);
            load_lds_16B(Bz + (size_t)(bn + r) * Kk + kt + (scb >> 1),
                         (char*)Bs[buf] + byte);
        }
    };

    stage(0, k0);
    __syncthreads();                                  // vmcnt(0) drain + barrier

    const int swz_rd = (lane & 7) << 4;
    int cur = 0;
    for (int t = 0; t < nt; ++t) {
        if (t + 1 < nt) stage(cur ^ 1, k0 + (t + 1) * BKK);   // prefetch in flight
        #pragma unroll
        for (int kk = 0; kk < 2; ++kk) {
            bf16x8 af[4], bfr[NF];
            int ro = lane & 15;
            int cob = kk * 64 + (lane >> 4) * 16;    // byte offset in row
            #pragma unroll
            for (int mi = 0; mi < 4; mi++) {
                int row = wr + mi * 16 + ro;
                af[mi] = *reinterpret_cast<const bf16x8*>(
                    (const char*)As[cur] + row * 128 + (cob ^ swz_rd));
            }
            #pragma unroll
            for (int ni = 0; ni < NF; ni++) {
                int row = wc + ni * 16 + ro;
                bfr[ni] = *reinterpret_cast<const bf16x8*>(
                    (const char*)Bs[cur] + row * 128 + (cob ^ swz_rd));
            }
            #pragma unroll
            for (int mi = 0; mi < 4; mi++)
                #pragma unroll
                for (int ni = 0; ni < NF; ni++)
                    acc[mi][ni] = __builtin_amdgcn_mfma_f32_16x16x32_bf16(
                        af[mi], bfr[ni], acc[mi][ni], 0, 0, 0);
        }
        __syncthreads();                              // drains prefetch, flips buf
        cur ^= 1;
    }

    int rbase = bm + wr + ((lane >> 4) << 2);
    int cbase = bn + wc + (lane & 15);
    #pragma unroll
    for (int mi = 0; mi < 4; mi++) {
        #pragma unroll
        for (int ni = 0; ni < NF; ni++) {
            int col = cbase + ni * 16;
            #pragma unroll
            for (int r = 0; r < 4; r++) {
                int row = rbase + mi * 16 + r;
                float v = acc[mi][ni][r];
                if constexpr (EPI == 0) {
                    ((bf16*)Cout)[(size_t)z * strideCz + (size_t)row * Nn + col] =
                        __float2bfloat16(v);
                } else if constexpr (EPI == 2) {
                    float t = v + bias[col];
                    float gel = 0.5f * t * (1.f + erff(t * 0.70710678118654752f));
                    ((bf16*)Cout)[(size_t)row * Nn + col] = __float2bfloat16(gel);
                } else if constexpr (EPI == 3) {
                    if (col < Nstore)
                        ((float*)Cout)[(size_t)row * Nstore + col] = v;
                } else { // EPI == 4
                    ((float*)Cout)[(size_t)z * strideCz + (size_t)row * Nn + col] = v;
                }
            }
        }
    }
}

// ---------------- fused flash attention (vector ALU, f32) ----------------
#define NEGMASK -1e10f
#define SM_SCALE 0.125f

__global__ __launch_bounds__(256) void attn_kernel(
    bf16* __restrict__ o, const bf16* __restrict__ qb,
    const bf16* __restrict__ kb, const bf16* __restrict__ vb)
{
    __shared__ __align__(16) float Ks[64][64];
    __shared__ __align__(16) float Vs[64][64];
    int tid = threadIdx.x;
    int wave = tid >> 6, lane = tid & 63;
    int g = lane >> 3, j = lane & 7;
    int idx = xcd_swz(blockIdx.x, gridDim.x);   // keep each (b,h)'s K/V on one XCD
    int qt = idx & 15;
    int bh = idx >> 4;
    int h = bh % H, b = bh / H;
    int qrow = qt * 32 + wave * 8 + g;
    const size_t base = ((size_t)b * SEQ) * DMODEL + h * HDIM;

    float Qf[8];
    {
        uint4 w = *reinterpret_cast<const uint4*>(qb + base + (size_t)qrow * DMODEL + j * 8);
        unpack8(w, Qf);
    }
    float O[8] = {0.f, 0.f, 0.f, 0.f, 0.f, 0.f, 0.f, 0.f};
    float mx = -INFINITY, sm = 0.f;

    for (int mt = 0; mt < SEQ; mt += 64) {
        __syncthreads();
        #pragma unroll
        for (int pass = 0; pass < 2; ++pass) {
            int t = tid + pass * 256;
            int r = t >> 3, c0 = (t & 7) * 8;
            uint4 wk = *reinterpret_cast<const uint4*>(kb + base + (size_t)(mt + r) * DMODEL + c0);
            uint4 wv = *reinterpret_cast<const uint4*>(vb + base + (size_t)(mt + r) * DMODEL + c0);
            float kf[8], vf[8];
            unpack8(wk, kf);
            unpack8(wv, vf);
            #pragma unroll
            for (int e = 0; e < 8; e++) { Ks[r][c0 + e] = kf[e]; Vs[r][c0 + e] = vf[e]; }
        }
        __syncthreads();

        float p[8];
        #pragma unroll
        for (int mi = 0; mi < 64; ++mi) {
            const float* kr = &Ks[mi][j * 8];
            float d = Qf[0] * kr[0];
            #pragma unroll
            for (int e = 1; e < 8; ++e) d = fmaf(Qf[e], kr[e], d);
            d += __shfl_xor(d, 1);
            d += __shfl_xor(d, 2);
            d += __shfl_xor(d, 4);
            float sval = ((mt + mi) >= qrow) ? (d + NEGMASK) * SM_SCALE : d * SM_SCALE;
            if ((mi & 7) == j) p[mi >> 3] = sval;
        }
        float tmax = p[0];
        #pragma unroll
        for (int i = 1; i < 8; i++) tmax = fmaxf(tmax, p[i]);
        tmax = fmaxf(tmax, __shfl_xor(tmax, 1));
        tmax = fmaxf(tmax, __shfl_xor(tmax, 2));
        tmax = fmaxf(tmax, __shfl_xor(tmax, 4));
        float nm = fmaxf(mx, tmax);
        float f = __expf(mx - nm);
        float ps = 0.f;
        #pragma unroll
        for (int i = 0; i < 8; i++) { p[i] = __expf(p[i] - nm); ps += p[i]; }
        ps += __shfl_xor(ps, 1);
        ps += __shfl_xor(ps, 2);
        ps += __shfl_xor(ps, 4);
        sm = sm * f + ps;
        #pragma unroll
        for (int e = 0; e < 8; e++) O[e] *= f;
        #pragma unroll
        for (int mi = 0; mi < 64; ++mi) {
            float pm = __shfl(p[mi >> 3], (g << 3) | (mi & 7), 64);
            const float* vr = &Vs[mi][j * 8];
            #pragma unroll
            for (int e = 0; e < 8; e++) O[e] = fmaf(pm, vr[e], O[e]);
        }
        mx = nm;
    }

    float inv = 1.f / sm;
    uint4 wout;
    wout.x = f2bf_bits(O[0] * inv) | (f2bf_bits(O[1] * inv) << 16);
    wout.y = f2bf_bits(O[2] * inv) | (f2bf_bits(O[3] * inv) << 16);
    wout.z = f2bf_bits(O[4] * inv) | (f2bf_bits(O[5] * inv) << 16);
    wout.w = f2bf_bits(O[6] * inv) | (f2bf_bits(O[7] * inv) << 16);
    *reinterpret_cast<uint4*>(o + base + (size_t)qrow * DMODEL + j * 8) = wout;
}

// ---------------- host orchestration ----------------
extern "C" void kernel_launch(void* const* d_in, const int* in_sizes, int n_in,
                              void* d_out, int out_size, void* d_ws, size_t ws_size,
                              hipStream_t stream)
{
    (void)in_sizes; (void)n_in; (void)out_size; (void)ws_size;
    const int*   tokens = (const int*)d_in[0];
    const float* E    = (const float*)d_in[1];
    const float* P    = (const float*)d_in[2];
    const float* Wq   = (const float*)d_in[3];
    const float* Wk   = (const float*)d_in[4];
    const float* Wv   = (const float*)d_in[5];
    const float* Wo   = (const float*)d_in[6];
    const float* bo   = (const float*)d_in[7];
    const float* g1   = (const float*)d_in[8];
    const float* b1   = (const float*)d_in[9];
    const float* g2   = (const float*)d_in[10];
    const float* b2   = (const float*)d_in[11];
    const float* W1   = (const float*)d_in[12];
    const float* bff1 = (const float*)d_in[13];
    const float* W2   = (const float*)d_in[14];
    const float* bff2 = (const float*)d_in[15];
    const float* gf   = (const float*)d_in[16];
    const float* bfin = (const float*)d_in[17];

    char* ws = (char*)d_ws;
    size_t off = 0;
    auto alloc = [&](size_t bytes) -> void* {
        void* p = ws + off;
        off += (bytes + 255) & ~(size_t)255;
        return p;
    };
    float* x     = (float*)alloc((size_t)MTOK * DMODEL * 4);
    bf16* hbuf   = (bf16*)alloc((size_t)MTOK * DMODEL * 2);
    bf16* qkv    = (bf16*)alloc((size_t)3 * MTOK * DMODEL * 2);
    bf16* obuf   = (bf16*)alloc((size_t)MTOK * DMODEL * 2);
    bf16* ffb    = (bf16*)alloc((size_t)MTOK * DFF * 2);
    float* part  = (float*)alloc((size_t)3 * MTOK * DMODEL * 4);
    bf16* Eb     = (bf16*)alloc((size_t)VPAD * DMODEL * 2);
    bf16* Wqkv_b = (bf16*)alloc((size_t)3 * L * DMODEL * DMODEL * 2);
    bf16* Wo_b   = (bf16*)alloc((size_t)L * DMODEL * DMODEL * 2);
    bf16* W1_b   = (bf16*)alloc((size_t)L * DFF * DMODEL * 2);
    bf16* W2_b   = (bf16*)alloc((size_t)L * DMODEL * DFF * 2);

    long nE  = (long)VOCAB * DMODEL;
    long nEp = (long)VPAD * DMODEL;
    cvt_pad_kernel<<<2048, 256, 0, stream>>>(Eb, E, nE, nEp);
    long nW = (long)L * DMODEL * DMODEL;
    cvt_pad_kernel<<<2048, 256, 0, stream>>>(Wqkv_b,          Wq, nW, nW);
    cvt_pad_kernel<<<2048, 256, 0, stream>>>(Wqkv_b + nW,     Wk, nW, nW);
    cvt_pad_kernel<<<2048, 256, 0, stream>>>(Wqkv_b + 2 * nW, Wv, nW, nW);
    cvt_pad_kernel<<<2048, 256, 0, stream>>>(Wo_b,            Wo, nW, nW);
    long nF = (long)L * DFF * DMODEL;
    cvt_pad_kernel<<<2048, 256, 0, stream>>>(W1_b, W1, nF, nF);
    cvt_pad_kernel<<<2048, 256, 0, stream>>>(W2_b, W2, nF, nF);

    embed_ln_kernel<<<MTOK, 256, 0, stream>>>(x, hbuf, tokens, E, P, g1, b1);

    const long pstride = (long)MTOK * DMODEL;
    for (int l = 0; l < L; ++l) {
        // QKV: M=2048, N=768, K=768, z-batched over {Q,K,V}; grid 192*3
        gemm_bt<64, 0><<<dim3(16 * 12, 1, 3), 256, 0, stream>>>(
            hbuf, Wqkv_b + (size_t)l * DMODEL * DMODEL, (long)L * DMODEL * DMODEL,
            qkv, pstride, nullptr, MTOK, DMODEL, DMODEL, 0, 0);
        attn_kernel<<<BATCH * H * (SEQ / 32), 256, 0, stream>>>(
            obuf, qkv, qkv + pstride, qkv + 2 * pstride);
        // proj: split-K 3 -> partials
        gemm_bt<64, 4><<<dim3(16 * 12, 1, 3), 256, 0, stream>>>(
            obuf, Wo_b + (size_t)l * DMODEL * DMODEL, 0,
            part, pstride, nullptr, MTOK, DMODEL, DMODEL, 0, DMODEL / 3);
        reduce_ln_kernel<<<MTOK, 256, 0, stream>>>(
            x, part, 3, bo + l * DMODEL, g2 + l * DMODEL, b2 + l * DMODEL, hbuf);
        // FF1: M=2048, N=3072, K=768, gelu; grid 768
        gemm_bt<64, 2><<<dim3(16 * 48, 1, 1), 256, 0, stream>>>(
            hbuf, W1_b + (size_t)l * DFF * DMODEL, 0,
            ffb, 0, bff1 + l * DFF, MTOK, DFF, DMODEL, 0, 0);
        // FF2: split-K 3 -> partials
        gemm_bt<64, 4><<<dim3(16 * 12, 1, 3), 256, 0, stream>>>(
            ffb, W2_b + (size_t)l * DMODEL * DFF, 0,
            part, pstride, nullptr, MTOK, DMODEL, DFF, 0, DFF / 3);
        const float* ng = (l < L - 1) ? (g1 + (l + 1) * DMODEL) : gf;
        const float* nb = (l < L - 1) ? (b1 + (l + 1) * DMODEL) : bfin;
        reduce_ln_kernel<<<MTOK, 256, 0, stream>>>(
            x, part, 3, bff2 + l * DMODEL, ng, nb, hbuf);
    }
    // LM head: M=2048, N=50304 (bounded store to 50257), K=768
    gemm_bt<128, 3><<<dim3(16 * 393, 1, 1), 256, 0, stream>>>(
        hbuf, Eb, 0, d_out, 0, nullptr, MTOK, VPAD, DMODEL, VOCAB, 0);
}

// Round 4
// 1736.320 us; speedup vs baseline: 2.3681x; 1.6992x over previous
//
#include <hip/hip_runtime.h>
#include <hip/hip_bf16.h>
#include <math.h>
#include <stdint.h>

#define L      12
#define H      12
#define DMODEL 768
#define HDIM   64
#define DFF    3072
#define VOCAB  50257
#define VPAD   50304   // 393 * 128
#define SEQ    512
#define BATCH  4
#define MTOK   2048    // BATCH*SEQ

typedef __hip_bfloat16 bf16;
typedef __bf16 bf16x8 __attribute__((ext_vector_type(8)));
typedef float  f32x4  __attribute__((ext_vector_type(4)));

__device__ inline float bfbits2f(unsigned int u) {
    return __builtin_bit_cast(float, u << 16);
}
__device__ inline unsigned int f2bf_bits(float f) {
    __hip_bfloat16 h = __float2bfloat16(f);
    return (unsigned int)__builtin_bit_cast(unsigned short, h);
}

typedef __attribute__((address_space(1))) unsigned int as1_uint;
typedef __attribute__((address_space(3))) unsigned int as3_uint;

__device__ inline void load_lds_16B(const void* g, void* l) {
    __builtin_amdgcn_global_load_lds((as1_uint*)(uintptr_t)g,
                                     (as3_uint*)(uintptr_t)l, 16, 0, 0);
}

// XCD-chunked bijective swizzle (nwg % 8 == 0 for every grid we launch)
__device__ inline int xcd_swz(int raw, int nwg) {
    return (raw & 7) * (nwg >> 3) + (raw >> 3);
}

// ---------------- f32 -> bf16 conversion, vectorized, with zero pad tail ------
__global__ void cvt_pad_kernel(bf16* __restrict__ dst, const float* __restrict__ src,
                               long ns, long nt) {
    long i8 = ((long)blockIdx.x * blockDim.x + threadIdx.x) * 8;
    long stride = (long)gridDim.x * blockDim.x * 8;
    for (; i8 < nt; i8 += stride) {
        uint4 out;
        if (i8 < ns) {
            float4 a = *reinterpret_cast<const float4*>(src + i8);
            float4 b = *reinterpret_cast<const float4*>(src + i8 + 4);
            out.x = f2bf_bits(a.x) | (f2bf_bits(a.y) << 16);
            out.y = f2bf_bits(a.z) | (f2bf_bits(a.w) << 16);
            out.z = f2bf_bits(b.x) | (f2bf_bits(b.y) << 16);
            out.w = f2bf_bits(b.z) | (f2bf_bits(b.w) << 16);
        } else {
            out = (uint4){0u, 0u, 0u, 0u};
        }
        *reinterpret_cast<uint4*>(dst + i8) = out;
    }
}

// ---------------- fused embedding + LayerNorm ----------------
__global__ __launch_bounds__(256) void embed_ln_kernel(
        float* __restrict__ x, bf16* __restrict__ hout,
        const int* __restrict__ tok, const float* __restrict__ E,
        const float* __restrict__ P, const float* __restrict__ g,
        const float* __restrict__ b) {
    int row = blockIdx.x, tid = threadIdx.x;
    int s = row % SEQ;
    size_t ebase = (size_t)tok[row] * DMODEL;
    float v[3];
    #pragma unroll
    for (int e = 0; e < 3; e++) {
        int c = tid + e * 256;
        v[e] = E[ebase + c] + P[s * DMODEL + c];
        x[(size_t)row * DMODEL + c] = v[e];
    }
    float s1 = v[0] + v[1] + v[2];
    float s2 = v[0] * v[0] + v[1] * v[1] + v[2] * v[2];
    #pragma unroll
    for (int o = 32; o > 0; o >>= 1) {
        s1 += __shfl_down(s1, o);
        s2 += __shfl_down(s2, o);
    }
    __shared__ float w1[4], w2[4];
    int wv = tid >> 6;
    if ((tid & 63) == 0) { w1[wv] = s1; w2[wv] = s2; }
    __syncthreads();
    s1 = w1[0] + w1[1] + w1[2] + w1[3];
    s2 = w2[0] + w2[1] + w2[2] + w2[3];
    float u    = s1 * (1.f / DMODEL);
    float var  = s2 * (1.f / DMODEL) - u * u;
    float rstd = rsqrtf(var + 1e-5f);
    size_t base = (size_t)row * DMODEL;
    #pragma unroll
    for (int e = 0; e < 3; e++) {
        int c = tid + e * 256;
        hout[base + c] = __float2bfloat16(g[c] * (v[e] - u) * rstd + b[c]);
    }
}

// ------- fused split-K reduce + bias + residual add + LayerNorm -> bf16 -------
__global__ __launch_bounds__(256) void reduce_ln_kernel(
        float* __restrict__ x, const float* __restrict__ part, int S,
        const float* __restrict__ bias, const float* __restrict__ g,
        const float* __restrict__ b, bf16* __restrict__ hout) {
    int row = blockIdx.x, tid = threadIdx.x;
    float v[3];
    #pragma unroll
    for (int e = 0; e < 3; e++) {
        int c = tid + e * 256;
        size_t idx = (size_t)row * DMODEL + c;
        float acc = x[idx] + bias[c];
        for (int s = 0; s < S; s++)
            acc += part[((size_t)s * MTOK + row) * DMODEL + c];
        v[e] = acc;
        x[idx] = acc;
    }
    float s1 = v[0] + v[1] + v[2];
    float s2 = v[0] * v[0] + v[1] * v[1] + v[2] * v[2];
    #pragma unroll
    for (int o = 32; o > 0; o >>= 1) {
        s1 += __shfl_down(s1, o);
        s2 += __shfl_down(s2, o);
    }
    __shared__ float w1[4], w2[4];
    int wv = tid >> 6;
    if ((tid & 63) == 0) { w1[wv] = s1; w2[wv] = s2; }
    __syncthreads();
    s1 = w1[0] + w1[1] + w1[2] + w1[3];
    s2 = w2[0] + w2[1] + w2[2] + w2[3];
    float u    = s1 * (1.f / DMODEL);
    float var  = s2 * (1.f / DMODEL) - u * u;
    float rstd = rsqrtf(var + 1e-5f);
    size_t base = (size_t)row * DMODEL;
    #pragma unroll
    for (int e = 0; e < 3; e++) {
        int c = tid + e * 256;
        hout[base + c] = __float2bfloat16(g[c] * (v[e] - u) * rstd + b[c]);
    }
}

// ---------------- GEMM: C[M,N] = A[M,K] * B[N,K]^T  (bf16 in, f32 acc) --------
// Double-buffered prefetch: stage(next) -> compute(cur) -> 1 barrier.
#define BM 128
#define BKK 64

template<int BN_, int EPI>
__global__ __launch_bounds__(256) void gemm_bt(
    const bf16* __restrict__ A, const bf16* __restrict__ Bmat, long strideBz,
    void* __restrict__ Cout, long strideCz,
    const float* __restrict__ bias,
    int Mm, int Nn, int Kk, int Nstore, int kslice)
{
    constexpr int NF = BN_ / 32;
    __shared__ __align__(16) bf16 As[2][BM * BKK];
    __shared__ __align__(16) bf16 Bs[2][BN_ * BKK];
    int tid = threadIdx.x;
    int lane = tid & 63, wave = tid >> 6;

    int Mtiles = Mm / BM;
    int id = xcd_swz(blockIdx.x, gridDim.x);
    int bm = (id % Mtiles) * BM;
    int bn = (id / Mtiles) * BN_;
    int z = blockIdx.z;
    const bf16* Bz = Bmat + (size_t)z * strideBz;
    int wr = (wave >> 1) * 64, wc = (wave & 1) * (BN_ / 2);

    int k0 = (EPI == 4) ? z * kslice : 0;
    int nt = ((EPI == 4) ? kslice : Kk) / BKK;

    f32x4 acc[4][NF];
    #pragma unroll
    for (int i = 0; i < 4; i++)
        #pragma unroll
        for (int j = 0; j < NF; j++) acc[i][j] = (f32x4){0.f, 0.f, 0.f, 0.f};

    auto stage = [&](int buf, int kt) {
        #pragma unroll
        for (int i = 0; i < 4; i++) {
            int byte = i * 4096 + tid * 16;
            int r = byte >> 7;
            int scb = (byte & 127) ^ ((r & 7) << 4);
            load_lds_16B(A + (size_t)(bm + r) * Kk + kt + (scb >> 1),
                         (char*)As[buf] + byte);
        }
        #pragma unroll
        for (int i = 0; i < BN_ / 32; i++) {
            int byte = i * 4096 + tid * 16;
            int r = byte >> 7;
            int scb = (byte & 127) ^ ((r & 7) << 4);
            load_lds_16B(Bz + (size_t)(bn + r) * Kk + kt + (scb >> 1),
                         (char*)Bs[buf] + byte);
        }
    };

    stage(0, k0);
    __syncthreads();

    const int swz_rd = (lane & 7) << 4;
    int cur = 0;
    for (int t = 0; t < nt; ++t) {
        if (t + 1 < nt) stage(cur ^ 1, k0 + (t + 1) * BKK);
        #pragma unroll
        for (int kk = 0; kk < 2; ++kk) {
            bf16x8 af[4], bfr[NF];
            int ro = lane & 15;
            int cob = kk * 64 + (lane >> 4) * 16;
            #pragma unroll
            for (int mi = 0; mi < 4; mi++) {
                int row = wr + mi * 16 + ro;
                af[mi] = *reinterpret_cast<const bf16x8*>(
                    (const char*)As[cur] + row * 128 + (cob ^ swz_rd));
            }
            #pragma unroll
            for (int ni = 0; ni < NF; ni++) {
                int row = wc + ni * 16 + ro;
                bfr[ni] = *reinterpret_cast<const bf16x8*>(
                    (const char*)Bs[cur] + row * 128 + (cob ^ swz_rd));
            }
            #pragma unroll
            for (int mi = 0; mi < 4; mi++)
                #pragma unroll
                for (int ni = 0; ni < NF; ni++)
                    acc[mi][ni] = __builtin_amdgcn_mfma_f32_16x16x32_bf16(
                        af[mi], bfr[ni], acc[mi][ni], 0, 0, 0);
        }
        __syncthreads();
        cur ^= 1;
    }

    int rbase = bm + wr + ((lane >> 4) << 2);
    int cbase = bn + wc + (lane & 15);
    #pragma unroll
    for (int mi = 0; mi < 4; mi++) {
        #pragma unroll
        for (int ni = 0; ni < NF; ni++) {
            int col = cbase + ni * 16;
            #pragma unroll
            for (int r = 0; r < 4; r++) {
                int row = rbase + mi * 16 + r;
                float v = acc[mi][ni][r];
                if constexpr (EPI == 0) {
                    ((bf16*)Cout)[(size_t)z * strideCz + (size_t)row * Nn + col] =
                        __float2bfloat16(v);
                } else if constexpr (EPI == 2) {
                    float t = v + bias[col];
                    float gel = 0.5f * t * (1.f + erff(t * 0.70710678118654752f));
                    ((bf16*)Cout)[(size_t)row * Nn + col] = __float2bfloat16(gel);
                } else if constexpr (EPI == 3) {
                    if (col < Nstore)
                        ((float*)Cout)[(size_t)row * Nstore + col] = v;
                } else { // EPI == 4
                    ((float*)Cout)[(size_t)z * strideCz + (size_t)row * Nn + col] = v;
                }
            }
        }
    }
}

// ---------------- MFMA flash attention ----------------
// Block: 64 q rows of one (b,h); 4 waves x 16 q rows. grid = B*H*8 (SEQ/64).
// Per kv tile (64 rows): K staged swizzled via global_load_lds; V staged
// TRANSPOSED (VT[d][kv], XOR-swizzled) via reg+ds_write_b32 pair-packing;
// QK^T (8 MFMA) -> in-register online softmax -> P via per-wave LDS -> PV (8 MFMA).
// Mask bit-identical to ref: (d + NEG)*scale on k >= q (f32 absorption makes
// row 0 uniform, matching np). qt=0 runs all 8 kv tiles (row 0 attends all);
// qt>0 runs qt+1 tiles (skipped tiles contribute exactly 0).
#define NEGMASK -1e10f
#define SM_SCALE 0.125f

__global__ __launch_bounds__(256) void attn_kernel(
    bf16* __restrict__ o, const bf16* __restrict__ qb,
    const bf16* __restrict__ kb, const bf16* __restrict__ vb)
{
    __shared__ __align__(16) bf16 K_lds[64 * 64];    // [kv][d], rows 128B, swizzled
    __shared__ __align__(16) bf16 VT_lds[64 * 64];   // [d][kv], rows 128B, swizzled
    __shared__ __align__(16) bf16 P_lds[4][16 * 64]; // per-wave [q][kv], swizzled

    int tid = threadIdx.x;
    int wave = tid >> 6, lane = tid & 63;
    int g = lane >> 4;        // 0..3
    int cq = lane & 15;       // 0..15
    int idx = xcd_swz(blockIdx.x, gridDim.x);
    int qt = idx & 7;
    int bh = idx >> 3;
    int h = bh % H, b = bh / H;
    int q0 = qt * 64;
    const size_t base = ((size_t)b * SEQ) * DMODEL + h * HDIM;

    // Q A-frags: lane holds Q[q0 + wave*16 + cq][kk*32 + g*8 .. +8]
    bf16x8 qa[2];
    #pragma unroll
    for (int kk = 0; kk < 2; kk++)
        qa[kk] = *reinterpret_cast<const bf16x8*>(
            qb + base + (size_t)(q0 + wave * 16 + cq) * DMODEL + kk * 32 + g * 8);

    f32x4 acc_o[4];
    #pragma unroll
    for (int df = 0; df < 4; df++) acc_o[df] = (f32x4){0.f, 0.f, 0.f, 0.f};
    float m_run[4] = {-INFINITY, -INFINITY, -INFINITY, -INFINITY};
    float l_run[4] = {0.f, 0.f, 0.f, 0.f};

    int ntiles = (qt == 0) ? (SEQ / 64) : (qt + 1);
    for (int t = 0; t < ntiles; ++t) {
        int mt = t * 64;
        __syncthreads();     // previous tile's LDS reads complete
        // ---- stage K (8 KB), source pre-swizzled ----
        #pragma unroll
        for (int i = 0; i < 2; i++) {
            int byte = i * 4096 + tid * 16;
            int r = byte >> 7;
            int scb = (byte & 127) ^ ((r & 7) << 4);
            load_lds_16B(kb + base + (size_t)(mt + r) * DMODEL + (scb >> 1),
                         (char*)K_lds + byte);
        }
        // ---- stage V^T: thread handles kv row-pair rp, d cols c0..c0+7 ----
        {
            int rp = tid & 31;
            int c0 = (tid >> 5) * 8;
            const bf16* v0p = vb + base + (size_t)(mt + 2 * rp) * DMODEL + c0;
            uint4 a = *reinterpret_cast<const uint4*>(v0p);
            uint4 bb = *reinterpret_cast<const uint4*>(v0p + DMODEL);
            unsigned int au[4] = {a.x, a.y, a.z, a.w};
            unsigned int bu[4] = {bb.x, bb.y, bb.z, bb.w};
            #pragma unroll
            for (int j = 0; j < 8; j++) {
                unsigned int lo = (j & 1) ? (au[j >> 1] >> 16) : (au[j >> 1] & 0xffffu);
                unsigned int hi = (j & 1) ? (bu[j >> 1] >> 16) : (bu[j >> 1] & 0xffffu);
                int d = c0 + j;
                int byte = d * 128 + ((rp * 4) ^ ((d & 7) << 4));
                *reinterpret_cast<unsigned int*>((char*)VT_lds + byte) = lo | (hi << 16);
            }
        }
        __syncthreads();     // drains gload_lds (vmcnt) + ds_writes (lgkm)

        // ---- QK^T: S[q][kv], C layout row=(g*4+r), col=cq ----
        f32x4 s[4];
        #pragma unroll
        for (int nf = 0; nf < 4; nf++) s[nf] = (f32x4){0.f, 0.f, 0.f, 0.f};
        #pragma unroll
        for (int kk = 0; kk < 2; kk++) {
            #pragma unroll
            for (int nf = 0; nf < 4; nf++) {
                int row = nf * 16 + cq;
                bf16x8 kf = *reinterpret_cast<const bf16x8*>(
                    (const char*)K_lds + row * 128 +
                    ((kk * 64 + g * 16) ^ ((row & 7) << 4)));
                s[nf] = __builtin_amdgcn_mfma_f32_16x16x32_bf16(qa[kk], kf, s[nf], 0, 0, 0);
            }
        }

        // ---- mask + scale + online softmax (rows r, cols cq x 4 nf) ----
        float p[4][4];   // [nf][r]
        #pragma unroll
        for (int r = 0; r < 4; r++) {
            int qg = q0 + wave * 16 + (g << 2) + r;
            float sv[4];
            float vmax = -INFINITY;
            #pragma unroll
            for (int nf = 0; nf < 4; nf++) {
                int kv = mt + nf * 16 + cq;
                float d = s[nf][r];
                sv[nf] = (kv >= qg) ? (d + NEGMASK) * SM_SCALE : d * SM_SCALE;
                vmax = fmaxf(vmax, sv[nf]);
            }
            vmax = fmaxf(vmax, __shfl_xor(vmax, 1));
            vmax = fmaxf(vmax, __shfl_xor(vmax, 2));
            vmax = fmaxf(vmax, __shfl_xor(vmax, 4));
            vmax = fmaxf(vmax, __shfl_xor(vmax, 8));
            float nm = fmaxf(m_run[r], vmax);
            float f = __expf(m_run[r] - nm);
            m_run[r] = nm;
            float ps = 0.f;
            #pragma unroll
            for (int nf = 0; nf < 4; nf++) {
                float pv = __expf(sv[nf] - nm);
                p[nf][r] = pv;
                ps += pv;
            }
            ps += __shfl_xor(ps, 1);
            ps += __shfl_xor(ps, 2);
            ps += __shfl_xor(ps, 4);
            ps += __shfl_xor(ps, 8);
            l_run[r] = l_run[r] * f + ps;
            #pragma unroll
            for (int df = 0; df < 4; df++) acc_o[df][r] *= f;
        }

        // ---- P -> per-wave LDS (bf16, swizzled), then A-frags ----
        #pragma unroll
        for (int nf = 0; nf < 4; nf++)
            #pragma unroll
            for (int r = 0; r < 4; r++) {
                int q = (g << 2) + r;
                int blog = nf * 32 + cq * 2;
                int byte = wave * 2048 + q * 128 + (blog ^ ((q & 7) << 4));
                *reinterpret_cast<unsigned short*>((char*)P_lds + byte) =
                    (unsigned short)f2bf_bits(p[nf][r]);
            }
        __syncthreads();     // lgkm drain (P_lds is per-wave; barrier is safe/simple)

        // ---- PV: O[q][d] += P[q][kv] * V[kv][d] (B-frags from VT rows) ----
        #pragma unroll
        for (int kk = 0; kk < 2; kk++) {
            bf16x8 pa = *reinterpret_cast<const bf16x8*>(
                (const char*)P_lds + wave * 2048 + cq * 128 +
                ((kk * 64 + g * 16) ^ ((cq & 7) << 4)));
            #pragma unroll
            for (int df = 0; df < 4; df++) {
                int row = df * 16 + cq;
                bf16x8 vf = *reinterpret_cast<const bf16x8*>(
                    (const char*)VT_lds + row * 128 +
                    ((kk * 64 + g * 16) ^ ((row & 7) << 4)));
                acc_o[df] = __builtin_amdgcn_mfma_f32_16x16x32_bf16(pa, vf, acc_o[df], 0, 0, 0);
            }
        }
    }

    // ---- epilogue: O / l -> bf16 obuf ----
    #pragma unroll
    for (int r = 0; r < 4; r++) {
        float inv = 1.f / l_run[r];
        int qg = q0 + wave * 16 + (g << 2) + r;
        #pragma unroll
        for (int df = 0; df < 4; df++) {
            o[base + (size_t)qg * DMODEL + df * 16 + cq] =
                __float2bfloat16(acc_o[df][r] * inv);
        }
    }
}

// ---------------- host orchestration ----------------
extern "C" void kernel_launch(void* const* d_in, const int* in_sizes, int n_in,
                              void* d_out, int out_size, void* d_ws, size_t ws_size,
                              hipStream_t stream)
{
    (void)in_sizes; (void)n_in; (void)out_size; (void)ws_size;
    const int*   tokens = (const int*)d_in[0];
    const float* E    = (const float*)d_in[1];
    const float* P    = (const float*)d_in[2];
    const float* Wq   = (const float*)d_in[3];
    const float* Wk   = (const float*)d_in[4];
    const float* Wv   = (const float*)d_in[5];
    const float* Wo   = (const float*)d_in[6];
    const float* bo   = (const float*)d_in[7];
    const float* g1   = (const float*)d_in[8];
    const float* b1   = (const float*)d_in[9];
    const float* g2   = (const float*)d_in[10];
    const float* b2   = (const float*)d_in[11];
    const float* W1   = (const float*)d_in[12];
    const float* bff1 = (const float*)d_in[13];
    const float* W2   = (const float*)d_in[14];
    const float* bff2 = (const float*)d_in[15];
    const float* gf   = (const float*)d_in[16];
    const float* bfin = (const float*)d_in[17];

    char* ws = (char*)d_ws;
    size_t off = 0;
    auto alloc = [&](size_t bytes) -> void* {
        void* p = ws + off;
        off += (bytes + 255) & ~(size_t)255;
        return p;
    };
    float* x     = (float*)alloc((size_t)MTOK * DMODEL * 4);
    bf16* hbuf   = (bf16*)alloc((size_t)MTOK * DMODEL * 2);
    bf16* qkv    = (bf16*)alloc((size_t)3 * MTOK * DMODEL * 2);
    bf16* obuf   = (bf16*)alloc((size_t)MTOK * DMODEL * 2);
    bf16* ffb    = (bf16*)alloc((size_t)MTOK * DFF * 2);
    float* part  = (float*)alloc((size_t)3 * MTOK * DMODEL * 4);
    bf16* Eb     = (bf16*)alloc((size_t)VPAD * DMODEL * 2);
    bf16* Wqkv_b = (bf16*)alloc((size_t)3 * L * DMODEL * DMODEL * 2);
    bf16* Wo_b   = (bf16*)alloc((size_t)L * DMODEL * DMODEL * 2);
    bf16* W1_b   = (bf16*)alloc((size_t)L * DFF * DMODEL * 2);
    bf16* W2_b   = (bf16*)alloc((size_t)L * DMODEL * DFF * 2);

    long nE  = (long)VOCAB * DMODEL;
    long nEp = (long)VPAD * DMODEL;
    cvt_pad_kernel<<<2048, 256, 0, stream>>>(Eb, E, nE, nEp);
    long nW = (long)L * DMODEL * DMODEL;
    cvt_pad_kernel<<<2048, 256, 0, stream>>>(Wqkv_b,          Wq, nW, nW);
    cvt_pad_kernel<<<2048, 256, 0, stream>>>(Wqkv_b + nW,     Wk, nW, nW);
    cvt_pad_kernel<<<2048, 256, 0, stream>>>(Wqkv_b + 2 * nW, Wv, nW, nW);
    cvt_pad_kernel<<<2048, 256, 0, stream>>>(Wo_b,            Wo, nW, nW);
    long nF = (long)L * DFF * DMODEL;
    cvt_pad_kernel<<<2048, 256, 0, stream>>>(W1_b, W1, nF, nF);
    cvt_pad_kernel<<<2048, 256, 0, stream>>>(W2_b, W2, nF, nF);

    embed_ln_kernel<<<MTOK, 256, 0, stream>>>(x, hbuf, tokens, E, P, g1, b1);

    const long pstride = (long)MTOK * DMODEL;
    for (int l = 0; l < L; ++l) {
        gemm_bt<64, 0><<<dim3(16 * 12, 1, 3), 256, 0, stream>>>(
            hbuf, Wqkv_b + (size_t)l * DMODEL * DMODEL, (long)L * DMODEL * DMODEL,
            qkv, pstride, nullptr, MTOK, DMODEL, DMODEL, 0, 0);
        attn_kernel<<<BATCH * H * (SEQ / 64), 256, 0, stream>>>(
            obuf, qkv, qkv + pstride, qkv + 2 * pstride);
        gemm_bt<64, 4><<<dim3(16 * 12, 1, 3), 256, 0, stream>>>(
            obuf, Wo_b + (size_t)l * DMODEL * DMODEL, 0,
            part, pstride, nullptr, MTOK, DMODEL, DMODEL, 0, DMODEL / 3);
        reduce_ln_kernel<<<MTOK, 256, 0, stream>>>(
            x, part, 3, bo + l * DMODEL, g2 + l * DMODEL, b2 + l * DMODEL, hbuf);
        gemm_bt<64, 2><<<dim3(16 * 48, 1, 1), 256, 0, stream>>>(
            hbuf, W1_b + (size_t)l * DFF * DMODEL, 0,
            ffb, 0, bff1 + l * DFF, MTOK, DFF, DMODEL, 0, 0);
        gemm_bt<64, 4><<<dim3(16 * 12, 1, 3), 256, 0, stream>>>(
            ffb, W2_b + (size_t)l * DMODEL * DFF, 0,
            part, pstride, nullptr, MTOK, DMODEL, DFF, 0, DFF / 3);
        const float* ng = (l < L - 1) ? (g1 + (l + 1) * DMODEL) : gf;
        const float* nb = (l < L - 1) ? (b1 + (l + 1) * DMODEL) : bfin;
        reduce_ln_kernel<<<MTOK, 256, 0, stream>>>(
            x, part, 3, bff2 + l * DMODEL, ng, nb, hbuf);
    }
    gemm_bt<128, 3><<<dim3(16 * 393, 1, 1), 256, 0, stream>>>(
        hbuf, Eb, 0, d_out, 0, nullptr, MTOK, VPAD, DMODEL, VOCAB, 0);
}